// Round 1
// baseline (759.371 us; speedup 1.0000x reference)
//
#include <hip/hip_runtime.h>
#include <hip/hip_bf16.h>

// Problem: p,q [64,64,25000] fp32. loss = sum_{rows} mask(row) * sum_v q*(log q - log p) / (D0*D1)
// mask(row) = 0 iff argmax_v p[row] == 0  <=>  p[row][0] >= max_v p[row].

#define VOCAB 25000
#define VOCAB4 6250          // 25000 / 4, exact
#define BLOCK 256

__global__ __launch_bounds__(BLOCK) void kl_row_kernel(
    const float* __restrict__ p, const float* __restrict__ q,
    float* __restrict__ partial)
{
    const int row = blockIdx.x;
    const size_t base = (size_t)row * VOCAB;
    // row byte offset = row * 100000, divisible by 16 -> float4 aligned
    const float4* __restrict__ p4 = reinterpret_cast<const float4*>(p + base);
    const float4* __restrict__ q4 = reinterpret_cast<const float4*>(q + base);

    const int tid = threadIdx.x;

    float sum  = 0.0f;
    float pmax = -1.0f;   // probabilities are positive

    for (int v = tid; v < VOCAB4; v += BLOCK) {
        float4 pv = p4[v];
        float4 qv = q4[v];
        sum += qv.x * (__logf(qv.x) - __logf(pv.x));
        sum += qv.y * (__logf(qv.y) - __logf(pv.y));
        sum += qv.z * (__logf(qv.z) - __logf(pv.z));
        sum += qv.w * (__logf(qv.w) - __logf(pv.w));
        float m01 = fmaxf(pv.x, pv.y);
        float m23 = fmaxf(pv.z, pv.w);
        pmax = fmaxf(pmax, fmaxf(m01, m23));
    }

    // wave(64) shuffle reduction
    #pragma unroll
    for (int off = 32; off > 0; off >>= 1) {
        sum  += __shfl_down(sum, off, 64);
        pmax  = fmaxf(pmax, __shfl_down(pmax, off, 64));
    }

    __shared__ float ssum[BLOCK / 64];
    __shared__ float smax[BLOCK / 64];
    const int wave = tid >> 6;
    const int lane = tid & 63;
    if (lane == 0) { ssum[wave] = sum; smax[wave] = pmax; }
    __syncthreads();

    if (tid == 0) {
        float s = ssum[0] + ssum[1] + ssum[2] + ssum[3];
        float m = fmaxf(fmaxf(smax[0], smax[1]), fmaxf(smax[2], smax[3]));
        float p0 = p[base];                 // L1/L2 hit (already fetched by thread 0)
        // mask = (argmax != 0). argmax==0 iff p0 == rowmax (first-occurrence rule).
        partial[row] = (p0 < m) ? s : 0.0f;
    }
}

__global__ __launch_bounds__(BLOCK) void kl_final_reduce(
    const float* __restrict__ partial, int rows, float* __restrict__ out)
{
    const int tid = threadIdx.x;
    float sum = 0.0f;
    for (int i = tid; i < rows; i += BLOCK) sum += partial[i];

    #pragma unroll
    for (int off = 32; off > 0; off >>= 1)
        sum += __shfl_down(sum, off, 64);

    __shared__ float ssum[BLOCK / 64];
    const int wave = tid >> 6;
    const int lane = tid & 63;
    if (lane == 0) ssum[wave] = sum;
    __syncthreads();

    if (tid == 0) {
        float s = ssum[0] + ssum[1] + ssum[2] + ssum[3];
        out[0] = s / (float)rows;
    }
}

extern "C" void kernel_launch(void* const* d_in, const int* in_sizes, int n_in,
                              void* d_out, int out_size, void* d_ws, size_t ws_size,
                              hipStream_t stream)
{
    const float* p = (const float*)d_in[0];
    const float* q = (const float*)d_in[1];
    float* out = (float*)d_out;
    float* partial = (float*)d_ws;          // rows * 4 bytes = 16 KB

    const int rows = in_sizes[0] / VOCAB;   // 64*64 = 4096

    kl_row_kernel<<<rows, BLOCK, 0, stream>>>(p, q, partial);
    kl_final_reduce<<<1, BLOCK, 0, stream>>>(partial, rows, out);
}

// Round 2
// 716.993 us; speedup vs baseline: 1.0591x; 1.0591x over previous
//
#include <hip/hip_runtime.h>
#include <hip/hip_bf16.h>

// p,q [64,64,25000] fp32. loss = sum_{rows} mask(row) * sum_v q*(log q - log p) / 4096
// mask(row) = 0 iff argmax_v p[row] == 0  <=>  p[row][0] >= max_v p[row].
//
// Memory-bound: 819.2 MB read -> ~130 us floor at 6.3 TB/s.
// This version: 4 independent nontemporal float4 loads per iter per thread,
// dual accumulators (break FMA dependency chain), nt to bypass L2 allocation
// for the once-streamed data.

#define VOCAB   25000
#define VOCAB4  6250          // 25000 / 4, exact; rows are 32B-aligned (100000 % 32 == 0)
#define BLOCK   256
#define FULL_ITERS 12         // 12 * (2*BLOCK) = 6144 chunks; remainder = 106

typedef float f4 __attribute__((ext_vector_type(4)));

__global__ __launch_bounds__(BLOCK) void kl_row_kernel(
    const float* __restrict__ p, const float* __restrict__ q,
    float* __restrict__ partial)
{
    const int row = blockIdx.x;
    const size_t base = (size_t)row * VOCAB;
    const f4* __restrict__ p4 = reinterpret_cast<const f4*>(p + base);
    const f4* __restrict__ q4 = reinterpret_cast<const f4*>(q + base);
    const int tid = threadIdx.x;

    // p[row][0], needed for the mask; load before streaming (only lane 0 uses it)
    float p0 = (tid == 0) ? p[base] : 0.0f;

    float sum0 = 0.f, sum1 = 0.f;
    float pmax0 = -1.f, pmax1 = -1.f;   // probabilities are positive

    int v = tid;
    #pragma unroll 2
    for (int i = 0; i < FULL_ITERS; ++i, v += 2 * BLOCK) {
        f4 pa = __builtin_nontemporal_load(&p4[v]);
        f4 pb = __builtin_nontemporal_load(&p4[v + BLOCK]);
        f4 qa = __builtin_nontemporal_load(&q4[v]);
        f4 qb = __builtin_nontemporal_load(&q4[v + BLOCK]);

        sum0 += qa[0] * (__logf(qa[0]) - __logf(pa[0]));
        sum0 += qa[1] * (__logf(qa[1]) - __logf(pa[1]));
        sum0 += qa[2] * (__logf(qa[2]) - __logf(pa[2]));
        sum0 += qa[3] * (__logf(qa[3]) - __logf(pa[3]));
        sum1 += qb[0] * (__logf(qb[0]) - __logf(pb[0]));
        sum1 += qb[1] * (__logf(qb[1]) - __logf(pb[1]));
        sum1 += qb[2] * (__logf(qb[2]) - __logf(pb[2]));
        sum1 += qb[3] * (__logf(qb[3]) - __logf(pb[3]));

        pmax0 = fmaxf(pmax0, fmaxf(fmaxf(pa[0], pa[1]), fmaxf(pa[2], pa[3])));
        pmax1 = fmaxf(pmax1, fmaxf(fmaxf(pb[0], pb[1]), fmaxf(pb[2], pb[3])));
    }

    // remainder: chunks 6144..6249 (106 chunks)
    if (tid < (VOCAB4 - FULL_ITERS * 2 * BLOCK)) {
        const int vr = FULL_ITERS * 2 * BLOCK + tid;
        f4 pa = __builtin_nontemporal_load(&p4[vr]);
        f4 qa = __builtin_nontemporal_load(&q4[vr]);
        sum0 += qa[0] * (__logf(qa[0]) - __logf(pa[0]));
        sum0 += qa[1] * (__logf(qa[1]) - __logf(pa[1]));
        sum0 += qa[2] * (__logf(qa[2]) - __logf(pa[2]));
        sum0 += qa[3] * (__logf(qa[3]) - __logf(pa[3]));
        pmax0 = fmaxf(pmax0, fmaxf(fmaxf(pa[0], pa[1]), fmaxf(pa[2], pa[3])));
    }

    float sum  = sum0 + sum1;
    float pmax = fmaxf(pmax0, pmax1);

    // wave(64) shuffle reduction
    #pragma unroll
    for (int off = 32; off > 0; off >>= 1) {
        sum  += __shfl_down(sum, off, 64);
        pmax  = fmaxf(pmax, __shfl_down(pmax, off, 64));
    }

    __shared__ float ssum[BLOCK / 64];
    __shared__ float smax[BLOCK / 64];
    const int wave = tid >> 6;
    const int lane = tid & 63;
    if (lane == 0) { ssum[wave] = sum; smax[wave] = pmax; }
    __syncthreads();

    if (tid == 0) {
        float s = ssum[0] + ssum[1] + ssum[2] + ssum[3];
        float m = fmaxf(fmaxf(smax[0], smax[1]), fmaxf(smax[2], smax[3]));
        // mask = (argmax != 0); argmax==0 iff p0 == rowmax (first-occurrence rule)
        partial[row] = (p0 < m) ? s : 0.0f;
    }
}

__global__ __launch_bounds__(BLOCK) void kl_final_reduce(
    const float* __restrict__ partial, int rows, float* __restrict__ out)
{
    const int tid = threadIdx.x;
    float sum = 0.0f;
    for (int i = tid; i < rows; i += BLOCK) sum += partial[i];

    #pragma unroll
    for (int off = 32; off > 0; off >>= 1)
        sum += __shfl_down(sum, off, 64);

    __shared__ float ssum[BLOCK / 64];
    const int wave = tid >> 6;
    const int lane = tid & 63;
    if (lane == 0) ssum[wave] = sum;
    __syncthreads();

    if (tid == 0) {
        float s = ssum[0] + ssum[1] + ssum[2] + ssum[3];
        out[0] = s / (float)rows;
    }
}

extern "C" void kernel_launch(void* const* d_in, const int* in_sizes, int n_in,
                              void* d_out, int out_size, void* d_ws, size_t ws_size,
                              hipStream_t stream)
{
    const float* p = (const float*)d_in[0];
    const float* q = (const float*)d_in[1];
    float* out = (float*)d_out;
    float* partial = (float*)d_ws;          // rows * 4 B = 16 KB

    const int rows = in_sizes[0] / VOCAB;   // 64*64 = 4096

    kl_row_kernel<<<rows, BLOCK, 0, stream>>>(p, q, partial);
    kl_final_reduce<<<1, BLOCK, 0, stream>>>(partial, rows, out);
}